// Round 9
// baseline (143.567 us; speedup 1.0000x reference)
//
#include <hip/hip_runtime.h>
#include <hip/hip_bf16.h>
#include <hip/hip_fp16.h>

// All float tensors fp32 (proven R1/R2). Output fp32.
// Tables store E* = exp(-logit) in FP16; edge computes
// sigma(a)-sigma(b) = (u-t)/((1+t)(1+u)) with t=ESP*ECS, u=EIP*ECI in packed
// fp16 (v_pk_*), 1 v_rcp_f16/channel. R9: persistent grid-strided edge kernel
// with 2-stage software pipeline (rows for i+1 and indices for i+2 in flight
// while computing i) to convert the 24% memory-stall time into overlap.
constexpr int EDGES = 250000;
constexpr int EMB   = 64;
constexpr int CNUM  = 128;
constexpr int NSTU  = 10000;
constexpr int NITEM = 50000;
constexpr int NCONC = 2048;

// workspace (_Float16): ESP | EIP | ECS | ECI | WH(w_pred fp16, 128)
constexpr size_t ESP_OFF = 0;
constexpr size_t EIP_OFF = ESP_OFF + (size_t)NSTU  * CNUM;
constexpr size_t ECS_OFF = EIP_OFF + (size_t)NITEM * CNUM;
constexpr size_t ECI_OFF = ECS_OFF + (size_t)NCONC * CNUM;
constexpr size_t WH_OFF  = ECI_OFF + (size_t)NCONC * CNUM;

constexpr float NEG_LOG2E = -1.44269504088896340736f;

// proj job space: one wave per 16-row strip (conc strips: one wave per table)
constexpr int STU_JOBS  = NSTU  / 16;            // 625
constexpr int ITEM_JOBS = NITEM / 16;            // 3125
constexpr int CONC_JOBS = (NCONC / 16) * 2;      // 256
constexpr int NJOBS     = STU_JOBS + ITEM_JOBS + CONC_JOBS;  // 4006
constexpr int PROJ_BLKS = (NJOBS + 3) / 4;

// edge kernel geometry: persistent, grid-strided over 4-edge groups
constexpr int NGROUPS    = EDGES / 4;            // 62500
constexpr int EDGE_BLKS  = 1024;
constexpr int NW         = EDGE_BLKS * 4;        // waves = 4096

typedef _Float16 h8 __attribute__((ext_vector_type(8)));
typedef _Float16 h4 __attribute__((ext_vector_type(4)));
typedef _Float16 h2 __attribute__((ext_vector_type(2)));
typedef float    f32x4 __attribute__((ext_vector_type(4)));

__device__ __forceinline__ h8 pack8(float4 lo, float4 hi) {
    h8 h;
    h[0] = (_Float16)lo.x; h[1] = (_Float16)lo.y;
    h[2] = (_Float16)lo.z; h[3] = (_Float16)lo.w;
    h[4] = (_Float16)hi.x; h[5] = (_Float16)hi.y;
    h[6] = (_Float16)hi.z; h[7] = (_Float16)hi.w;
    return h;
}

__device__ __forceinline__ _Float16 rcp16(_Float16 x) {
#if __has_builtin(__builtin_amdgcn_rcph)
    return __builtin_amdgcn_rcph(x);
#else
    return (_Float16)__builtin_amdgcn_rcpf((float)x);
#endif
}

template <int CTRL>
__device__ __forceinline__ float dppadd(float x) {
    return x + __int_as_float(__builtin_amdgcn_update_dpp(
        0, __float_as_int(x), CTRL, 0xf, 0xf, true));
}

// ---- projection via MFMA: O[r,c] = exp(-dot(F[r,:], W[c, wcol:wcol+64])) ---
__global__ __launch_bounds__(256) void proj_mfma(
        const float* __restrict__ stuF, const float* __restrict__ itemF,
        const float* __restrict__ concF,
        const float* __restrict__ W_stu, const float* __restrict__ W_item,
        const float* __restrict__ w_pred,
        _Float16* __restrict__ ESP, _Float16* __restrict__ EIP,
        _Float16* __restrict__ ECS, _Float16* __restrict__ ECI,
        _Float16* __restrict__ WH) {
    const int tid  = threadIdx.x;
    const int lane = tid & 63;
    const int job  = blockIdx.x * 4 + (tid >> 6);
    if (job >= NJOBS) return;

    if (job == 0) {  // one wave converts w_pred (128 f32) to fp16 once
        const float2 wv2 = ((const float2*)w_pred)[lane];
        h2 wh; wh[0] = (_Float16)wv2.x; wh[1] = (_Float16)wv2.y;
        *(h2*)(WH + 2 * lane) = wh;
    }

    const float* F; const float* W; _Float16* O; int strip, wcol;
    if (job < STU_JOBS) {
        F = stuF;  W = W_stu;  O = ESP; strip = job; wcol = 0;
    } else if (job < STU_JOBS + ITEM_JOBS) {
        F = itemF; W = W_item; O = EIP; strip = job - STU_JOBS; wcol = 0;
    } else {
        const int g = job - STU_JOBS - ITEM_JOBS;
        F = concF; W = (g & 1) ? W_item : W_stu; O = (g & 1) ? ECI : ECS;
        strip = g >> 1; wcol = EMB;
    }

    const int m = lane & 15;       // A row / B channel / D col
    const int q = lane >> 4;       // quad
    const int row = strip * 16 + m;

    const float4* fa = (const float4*)(F + (size_t)row * EMB + q * 8);
    const float4* fb = (const float4*)(F + (size_t)row * EMB + 32 + q * 8);
    const h8 A0 = pack8(fa[0], fa[1]);
    const h8 A1 = pack8(fb[0], fb[1]);

    const int orow = strip * 16 + q * 4;

#pragma unroll
    for (int ct = 0; ct < 8; ++ct) {
        const int ch = ct * 16 + m;
        const float* wr = W + (size_t)ch * (2 * EMB) + wcol;
        const float4* wb0 = (const float4*)(wr + q * 8);
        const float4* wb1 = (const float4*)(wr + 32 + q * 8);
        const h8 B0 = pack8(wb0[0], wb0[1]);
        const h8 B1 = pack8(wb1[0], wb1[1]);

        f32x4 acc = {0.f, 0.f, 0.f, 0.f};
        acc = __builtin_amdgcn_mfma_f32_16x16x32_f16(A0, B0, acc, 0, 0, 0);
        acc = __builtin_amdgcn_mfma_f32_16x16x32_f16(A1, B1, acc, 0, 0, 0);

#pragma unroll
        for (int r = 0; r < 4; ++r) {
            const float e = __builtin_amdgcn_exp2f(acc[r] * NEG_LOG2E);
            O[(size_t)(orow + r) * CNUM + ct * 16 + m] = (_Float16)e;
        }
    }
}

__device__ __forceinline__ float sigm(float x) {
    return __builtin_amdgcn_rcpf(1.f + __builtin_amdgcn_exp2f(x * NEG_LOG2E));
}

// ---- edge phase --------------------------------------------------------
struct EIdx { int s, it; int4 c; };
struct ERows { h8 es, ei, cs0, ci0, cs1, ci1, cs2, ci2, cs3, ci3; };

__device__ __forceinline__ EIdx load_idx(
        int g, int sub,
        const int* __restrict__ stu_idx, const int* __restrict__ item_idx,
        const int4* __restrict__ conc_idx) {
    const int e = min(g, NGROUPS - 1) * 4 + sub;
    EIdx x;
    x.s  = stu_idx[e];
    x.it = item_idx[e];
    x.c  = conc_idx[e];
    return x;
}

__device__ __forceinline__ ERows load_rows(
        const EIdx& x, int li,
        const _Float16* __restrict__ ESP, const _Float16* __restrict__ EIP,
        const _Float16* __restrict__ ECS, const _Float16* __restrict__ ECI) {
    ERows r;
    r.es  = *(const h8*)(ESP + (size_t)x.s   * CNUM + li * 8);
    r.ei  = *(const h8*)(EIP + (size_t)x.it  * CNUM + li * 8);
    r.cs0 = *(const h8*)(ECS + (size_t)x.c.x * CNUM + li * 8);
    r.ci0 = *(const h8*)(ECI + (size_t)x.c.x * CNUM + li * 8);
    r.cs1 = *(const h8*)(ECS + (size_t)x.c.y * CNUM + li * 8);
    r.ci1 = *(const h8*)(ECI + (size_t)x.c.y * CNUM + li * 8);
    r.cs2 = *(const h8*)(ECS + (size_t)x.c.z * CNUM + li * 8);
    r.ci2 = *(const h8*)(ECI + (size_t)x.c.z * CNUM + li * 8);
    r.cs3 = *(const h8*)(ECS + (size_t)x.c.w * CNUM + li * 8);
    r.ci3 = *(const h8*)(ECI + (size_t)x.c.w * CNUM + li * 8);
    return r;
}

__device__ __forceinline__ float chan8(const h8 es, const h8 ei,
                                       const h8 cs, const h8 ci,
                                       const h8 w8, const h8 ONE) {
    const h8 t   = es * cs;
    const h8 u   = ei * ci;
    const h8 den = (t + ONE) * (u + ONE);
    const h8 num = w8 * (u - t);
    h8 r;
#pragma unroll
    for (int i = 0; i < 8; ++i) r[i] = num[i] * rcp16(den[i]);
    const h4 q4 = __builtin_shufflevector(r, r, 0, 1, 2, 3)
                + __builtin_shufflevector(r, r, 4, 5, 6, 7);
    const h2 q2 = __builtin_shufflevector(q4, q4, 0, 1)
                + __builtin_shufflevector(q4, q4, 2, 3);
    return (float)q2[0] + (float)q2[1];
}

__device__ __forceinline__ void compute_store(
        const ERows& r, int g, int sub, int li,
        const h8 w8, const h8 ONE, float b, float* __restrict__ out) {
    float p[4];
    p[0] = chan8(r.es, r.ei, r.cs0, r.ci0, w8, ONE);
    p[1] = chan8(r.es, r.ei, r.cs1, r.ci1, w8, ONE);
    p[2] = chan8(r.es, r.ei, r.cs2, r.ci2, w8, ONE);
    p[3] = chan8(r.es, r.ei, r.cs3, r.ci3, w8, ONE);

    // 16-lane sum via DPP butterfly (xor-basis {1,2,7,15} spans the group)
#pragma unroll
    for (int j = 0; j < 4; ++j) p[j] = dppadd<0xB1>(p[j]);
#pragma unroll
    for (int j = 0; j < 4; ++j) p[j] = dppadd<0x4E>(p[j]);
#pragma unroll
    for (int j = 0; j < 4; ++j) p[j] = dppadd<0x141>(p[j]);
#pragma unroll
    for (int j = 0; j < 4; ++j) p[j] = dppadd<0x140>(p[j]);

    const float res = 0.25f * (sigm(p[0] + b) + sigm(p[1] + b) +
                               sigm(p[2] + b) + sigm(p[3] + b));
    if (li == 0) out[g * 4 + sub] = res;
}

__global__ __launch_bounds__(256) void edge_kernel(
        const int*  __restrict__ stu_idx,
        const int*  __restrict__ item_idx,
        const int4* __restrict__ conc_idx,
        const _Float16* __restrict__ ESP,
        const _Float16* __restrict__ EIP,
        const _Float16* __restrict__ ECS,
        const _Float16* __restrict__ ECI,
        const _Float16* __restrict__ WH,
        const float* __restrict__ b_pred,
        float* __restrict__ out) {
    const int lane = threadIdx.x & 63;
    const int wid  = (blockIdx.x * blockDim.x + threadIdx.x) >> 6;
    const int sub  = lane >> 4;
    const int li   = lane & 15;

    const h8 w8 = *(const h8*)(WH + li * 8);
    const float b = b_pred[0];
    const h8 ONE = {(_Float16)1, (_Float16)1, (_Float16)1, (_Float16)1,
                    (_Float16)1, (_Float16)1, (_Float16)1, (_Float16)1};

    // 2-stage pipeline: rows(i+1), idx(i+2) in flight while computing i.
    int g = wid;
    EIdx  ia = load_idx(g, sub, stu_idx, item_idx, conc_idx);
    ERows ra = load_rows(ia, li, ESP, EIP, ECS, ECI);
    EIdx  ib = load_idx(g + NW, sub, stu_idx, item_idx, conc_idx);

    for (; g < NGROUPS; g += 2 * NW) {
        ERows rb = load_rows(ib, li, ESP, EIP, ECS, ECI);        // g+NW
        ia = load_idx(g + 2 * NW, sub, stu_idx, item_idx, conc_idx);
        compute_store(ra, g, sub, li, w8, ONE, b, out);          // g (valid)

        ra = load_rows(ia, li, ESP, EIP, ECS, ECI);              // g+2NW
        ib = load_idx(g + 3 * NW, sub, stu_idx, item_idx, conc_idx);
        if (g + NW < NGROUPS)
            compute_store(rb, g + NW, sub, li, w8, ONE, b, out); // g+NW
    }
}

extern "C" void kernel_launch(void* const* d_in, const int* in_sizes, int n_in,
                              void* d_out, int out_size, void* d_ws, size_t ws_size,
                              hipStream_t stream) {
    const int* stu_idx  = (const int*)d_in[0];
    const int* item_idx = (const int*)d_in[1];
    const int* conc_idx = (const int*)d_in[2];
    const float* stu_fusion     = (const float*)d_in[3];
    const float* item_fusion    = (const float*)d_in[4];
    const float* concept_fusion = (const float*)d_in[5];
    const float* W_stu          = (const float*)d_in[6];
    const float* W_item         = (const float*)d_in[7];
    const float* w_pred         = (const float*)d_in[8];
    const float* b_pred         = (const float*)d_in[9];
    float* out = (float*)d_out;

    _Float16* ESP = (_Float16*)d_ws + ESP_OFF;
    _Float16* EIP = (_Float16*)d_ws + EIP_OFF;
    _Float16* ECS = (_Float16*)d_ws + ECS_OFF;
    _Float16* ECI = (_Float16*)d_ws + ECI_OFF;
    _Float16* WH  = (_Float16*)d_ws + WH_OFF;

    proj_mfma<<<PROJ_BLKS, 256, 0, stream>>>(
        stu_fusion, item_fusion, concept_fusion, W_stu, W_item, w_pred,
        ESP, EIP, ECS, ECI, WH);

    edge_kernel<<<EDGE_BLKS, 256, 0, stream>>>(
        stu_idx, item_idx, (const int4*)conc_idx,
        ESP, EIP, ECS, ECI, WH, b_pred, out);
}

// Round 10
// 137.487 us; speedup vs baseline: 1.0442x; 1.0442x over previous
//
#include <hip/hip_runtime.h>
#include <hip/hip_bf16.h>
#include <hip/hip_fp16.h>

// All float tensors fp32 (proven R1/R2). Output fp32.
// Tables store E* = exp(-logit) in FP16; edge computes
// sigma(a)-sigma(b) = (u-t)/((1+t)(1+u)) with t=ESP*ECS, u=EIP*ECI in packed
// fp16 (v_pk_*), 1 v_rcp_f16/channel. R10: R8 structure (oversubscribed
// launch — R9's persistent pipeline starved TLP and regressed) + 2 adjacent
// 4-edge groups per wave: all 20 row-loads issue before the first compute,
// halving per-group memory stall while keeping the grid oversubscribed.
constexpr int EDGES = 250000;
constexpr int EMB   = 64;
constexpr int CNUM  = 128;
constexpr int NSTU  = 10000;
constexpr int NITEM = 50000;
constexpr int NCONC = 2048;

// workspace (_Float16): ESP | EIP | ECS | ECI | WH(w_pred fp16, 128)
constexpr size_t ESP_OFF = 0;
constexpr size_t EIP_OFF = ESP_OFF + (size_t)NSTU  * CNUM;
constexpr size_t ECS_OFF = EIP_OFF + (size_t)NITEM * CNUM;
constexpr size_t ECI_OFF = ECS_OFF + (size_t)NCONC * CNUM;
constexpr size_t WH_OFF  = ECI_OFF + (size_t)NCONC * CNUM;

constexpr float NEG_LOG2E = -1.44269504088896340736f;

// proj job space: one wave per 16-row strip (conc strips: one wave per table)
constexpr int STU_JOBS  = NSTU  / 16;            // 625
constexpr int ITEM_JOBS = NITEM / 16;            // 3125
constexpr int CONC_JOBS = (NCONC / 16) * 2;      // 256
constexpr int NJOBS     = STU_JOBS + ITEM_JOBS + CONC_JOBS;  // 4006
constexpr int PROJ_BLKS = (NJOBS + 3) / 4;

// edge geometry: 2 adjacent 4-edge groups per wave
constexpr int NGROUPS   = EDGES / 4;             // 62500
constexpr int NWJOBS    = NGROUPS / 2;           // 31250 waves
constexpr int EDGE_BLKS = (NWJOBS + 3) / 4;      // 7813 blocks

typedef _Float16 h8 __attribute__((ext_vector_type(8)));
typedef _Float16 h4 __attribute__((ext_vector_type(4)));
typedef _Float16 h2 __attribute__((ext_vector_type(2)));
typedef float    f32x4 __attribute__((ext_vector_type(4)));

__device__ __forceinline__ h8 pack8(float4 lo, float4 hi) {
    h8 h;
    h[0] = (_Float16)lo.x; h[1] = (_Float16)lo.y;
    h[2] = (_Float16)lo.z; h[3] = (_Float16)lo.w;
    h[4] = (_Float16)hi.x; h[5] = (_Float16)hi.y;
    h[6] = (_Float16)hi.z; h[7] = (_Float16)hi.w;
    return h;
}

__device__ __forceinline__ _Float16 rcp16(_Float16 x) {
#if __has_builtin(__builtin_amdgcn_rcph)
    return __builtin_amdgcn_rcph(x);
#else
    return (_Float16)__builtin_amdgcn_rcpf((float)x);
#endif
}

template <int CTRL>
__device__ __forceinline__ float dppadd(float x) {
    return x + __int_as_float(__builtin_amdgcn_update_dpp(
        0, __float_as_int(x), CTRL, 0xf, 0xf, true));
}

// ---- projection via MFMA: O[r,c] = exp(-dot(F[r,:], W[c, wcol:wcol+64])) ---
__global__ __launch_bounds__(256) void proj_mfma(
        const float* __restrict__ stuF, const float* __restrict__ itemF,
        const float* __restrict__ concF,
        const float* __restrict__ W_stu, const float* __restrict__ W_item,
        const float* __restrict__ w_pred,
        _Float16* __restrict__ ESP, _Float16* __restrict__ EIP,
        _Float16* __restrict__ ECS, _Float16* __restrict__ ECI,
        _Float16* __restrict__ WH) {
    const int tid  = threadIdx.x;
    const int lane = tid & 63;
    const int job  = blockIdx.x * 4 + (tid >> 6);
    if (job >= NJOBS) return;

    if (job == 0) {  // one wave converts w_pred (128 f32) to fp16 once
        const float2 wv2 = ((const float2*)w_pred)[lane];
        h2 wh; wh[0] = (_Float16)wv2.x; wh[1] = (_Float16)wv2.y;
        *(h2*)(WH + 2 * lane) = wh;
    }

    const float* F; const float* W; _Float16* O; int strip, wcol;
    if (job < STU_JOBS) {
        F = stuF;  W = W_stu;  O = ESP; strip = job; wcol = 0;
    } else if (job < STU_JOBS + ITEM_JOBS) {
        F = itemF; W = W_item; O = EIP; strip = job - STU_JOBS; wcol = 0;
    } else {
        const int g = job - STU_JOBS - ITEM_JOBS;
        F = concF; W = (g & 1) ? W_item : W_stu; O = (g & 1) ? ECI : ECS;
        strip = g >> 1; wcol = EMB;
    }

    const int m = lane & 15;       // A row / B channel / D col
    const int q = lane >> 4;       // quad
    const int row = strip * 16 + m;

    const float4* fa = (const float4*)(F + (size_t)row * EMB + q * 8);
    const float4* fb = (const float4*)(F + (size_t)row * EMB + 32 + q * 8);
    const h8 A0 = pack8(fa[0], fa[1]);
    const h8 A1 = pack8(fb[0], fb[1]);

    const int orow = strip * 16 + q * 4;

#pragma unroll
    for (int ct = 0; ct < 8; ++ct) {
        const int ch = ct * 16 + m;
        const float* wr = W + (size_t)ch * (2 * EMB) + wcol;
        const float4* wb0 = (const float4*)(wr + q * 8);
        const float4* wb1 = (const float4*)(wr + 32 + q * 8);
        const h8 B0 = pack8(wb0[0], wb0[1]);
        const h8 B1 = pack8(wb1[0], wb1[1]);

        f32x4 acc = {0.f, 0.f, 0.f, 0.f};
        acc = __builtin_amdgcn_mfma_f32_16x16x32_f16(A0, B0, acc, 0, 0, 0);
        acc = __builtin_amdgcn_mfma_f32_16x16x32_f16(A1, B1, acc, 0, 0, 0);

#pragma unroll
        for (int r = 0; r < 4; ++r) {
            const float e = __builtin_amdgcn_exp2f(acc[r] * NEG_LOG2E);
            O[(size_t)(orow + r) * CNUM + ct * 16 + m] = (_Float16)e;
        }
    }
}

__device__ __forceinline__ float sigm(float x) {
    return __builtin_amdgcn_rcpf(1.f + __builtin_amdgcn_exp2f(x * NEG_LOG2E));
}

// ---- edge phase --------------------------------------------------------
struct EIdx { int s, it; int4 c; };
struct ERows { h8 es, ei, cs0, ci0, cs1, ci1, cs2, ci2, cs3, ci3; };

__device__ __forceinline__ EIdx load_idx(
        int g, int sub,
        const int* __restrict__ stu_idx, const int* __restrict__ item_idx,
        const int4* __restrict__ conc_idx) {
    const int e = g * 4 + sub;
    EIdx x;
    x.s  = stu_idx[e];
    x.it = item_idx[e];
    x.c  = conc_idx[e];
    return x;
}

__device__ __forceinline__ ERows load_rows(
        const EIdx& x, int li,
        const _Float16* __restrict__ ESP, const _Float16* __restrict__ EIP,
        const _Float16* __restrict__ ECS, const _Float16* __restrict__ ECI) {
    ERows r;
    r.es  = *(const h8*)(ESP + (size_t)x.s   * CNUM + li * 8);
    r.ei  = *(const h8*)(EIP + (size_t)x.it  * CNUM + li * 8);
    r.cs0 = *(const h8*)(ECS + (size_t)x.c.x * CNUM + li * 8);
    r.ci0 = *(const h8*)(ECI + (size_t)x.c.x * CNUM + li * 8);
    r.cs1 = *(const h8*)(ECS + (size_t)x.c.y * CNUM + li * 8);
    r.ci1 = *(const h8*)(ECI + (size_t)x.c.y * CNUM + li * 8);
    r.cs2 = *(const h8*)(ECS + (size_t)x.c.z * CNUM + li * 8);
    r.ci2 = *(const h8*)(ECI + (size_t)x.c.z * CNUM + li * 8);
    r.cs3 = *(const h8*)(ECS + (size_t)x.c.w * CNUM + li * 8);
    r.ci3 = *(const h8*)(ECI + (size_t)x.c.w * CNUM + li * 8);
    return r;
}

__device__ __forceinline__ float chan8(const h8 es, const h8 ei,
                                       const h8 cs, const h8 ci,
                                       const h8 w8, const h8 ONE) {
    const h8 t   = es * cs;
    const h8 u   = ei * ci;
    const h8 den = (t + ONE) * (u + ONE);
    const h8 num = w8 * (u - t);
    h8 r;
#pragma unroll
    for (int i = 0; i < 8; ++i) r[i] = num[i] * rcp16(den[i]);
    const h4 q4 = __builtin_shufflevector(r, r, 0, 1, 2, 3)
                + __builtin_shufflevector(r, r, 4, 5, 6, 7);
    const h2 q2 = __builtin_shufflevector(q4, q4, 0, 1)
                + __builtin_shufflevector(q4, q4, 2, 3);
    return (float)q2[0] + (float)q2[1];
}

__device__ __forceinline__ void compute_store(
        const ERows& r, int g, int sub, int li,
        const h8 w8, const h8 ONE, float b, float* __restrict__ out) {
    float p[4];
    p[0] = chan8(r.es, r.ei, r.cs0, r.ci0, w8, ONE);
    p[1] = chan8(r.es, r.ei, r.cs1, r.ci1, w8, ONE);
    p[2] = chan8(r.es, r.ei, r.cs2, r.ci2, w8, ONE);
    p[3] = chan8(r.es, r.ei, r.cs3, r.ci3, w8, ONE);

    // 16-lane sum via DPP butterfly (xor-basis {1,2,7,15} spans the group)
#pragma unroll
    for (int j = 0; j < 4; ++j) p[j] = dppadd<0xB1>(p[j]);
#pragma unroll
    for (int j = 0; j < 4; ++j) p[j] = dppadd<0x4E>(p[j]);
#pragma unroll
    for (int j = 0; j < 4; ++j) p[j] = dppadd<0x141>(p[j]);
#pragma unroll
    for (int j = 0; j < 4; ++j) p[j] = dppadd<0x140>(p[j]);

    const float res = 0.25f * (sigm(p[0] + b) + sigm(p[1] + b) +
                               sigm(p[2] + b) + sigm(p[3] + b));
    if (li == 0) out[g * 4 + sub] = res;
}

__global__ __launch_bounds__(256) void edge_kernel(
        const int*  __restrict__ stu_idx,
        const int*  __restrict__ item_idx,
        const int4* __restrict__ conc_idx,
        const _Float16* __restrict__ ESP,
        const _Float16* __restrict__ EIP,
        const _Float16* __restrict__ ECS,
        const _Float16* __restrict__ ECI,
        const _Float16* __restrict__ WH,
        const float* __restrict__ b_pred,
        float* __restrict__ out) {
    const int lane = threadIdx.x & 63;
    const int wid  = (blockIdx.x * blockDim.x + threadIdx.x) >> 6;
    const int sub  = lane >> 4;
    const int li   = lane & 15;
    if (wid >= NWJOBS) return;

    const h8 w8 = *(const h8*)(WH + li * 8);
    const float b = b_pred[0];
    const h8 ONE = {(_Float16)1, (_Float16)1, (_Float16)1, (_Float16)1,
                    (_Float16)1, (_Float16)1, (_Float16)1, (_Float16)1};

    const int g0 = wid * 2, g1 = g0 + 1;

    // issue ALL loads for both groups before any compute: compute(g0)
    // overlaps g1's in-flight row gathers.
    const EIdx  i0 = load_idx(g0, sub, stu_idx, item_idx, conc_idx);
    const EIdx  i1 = load_idx(g1, sub, stu_idx, item_idx, conc_idx);
    const ERows r0 = load_rows(i0, li, ESP, EIP, ECS, ECI);
    const ERows r1 = load_rows(i1, li, ESP, EIP, ECS, ECI);

    compute_store(r0, g0, sub, li, w8, ONE, b, out);
    compute_store(r1, g1, sub, li, w8, ONE, b, out);
}

extern "C" void kernel_launch(void* const* d_in, const int* in_sizes, int n_in,
                              void* d_out, int out_size, void* d_ws, size_t ws_size,
                              hipStream_t stream) {
    const int* stu_idx  = (const int*)d_in[0];
    const int* item_idx = (const int*)d_in[1];
    const int* conc_idx = (const int*)d_in[2];
    const float* stu_fusion     = (const float*)d_in[3];
    const float* item_fusion    = (const float*)d_in[4];
    const float* concept_fusion = (const float*)d_in[5];
    const float* W_stu          = (const float*)d_in[6];
    const float* W_item         = (const float*)d_in[7];
    const float* w_pred         = (const float*)d_in[8];
    const float* b_pred         = (const float*)d_in[9];
    float* out = (float*)d_out;

    _Float16* ESP = (_Float16*)d_ws + ESP_OFF;
    _Float16* EIP = (_Float16*)d_ws + EIP_OFF;
    _Float16* ECS = (_Float16*)d_ws + ECS_OFF;
    _Float16* ECI = (_Float16*)d_ws + ECI_OFF;
    _Float16* WH  = (_Float16*)d_ws + WH_OFF;

    proj_mfma<<<PROJ_BLKS, 256, 0, stream>>>(
        stu_fusion, item_fusion, concept_fusion, W_stu, W_item, w_pred,
        ESP, EIP, ECS, ECI, WH);

    edge_kernel<<<EDGE_BLKS, 256, 0, stream>>>(
        stu_idx, item_idx, (const int4*)conc_idx,
        ESP, EIP, ECS, ECI, WH, b_pred, out);
}